// Round 5
// baseline (216.061 us; speedup 1.0000x reference)
//
#include <hip/hip_runtime.h>
#include <math.h>

// CalWeight: out[b,j] = phi[b,j] - phi[b,(j+1)%N]
//   phi[b,j] = atan2(verts_y[b,j] - row[b], verts_x[b,j] - col[b])
// x layout per row: [col, row, v0x, v0y, ..., v1023x, v1023y], stride 2050 f32.
//
// R4 evidence: OCML atan2 vs 20-op poly atan2 -> identical dur_us, so the
// kernel is memory-bound (~201.3 MB irreducible -> ~30 us floor at 6.8 TB/s)
// and bench dur_us (~205 us) is dominated by harness restore/poison work.
// This round removes the last structural overhead: the LDS round-trip and
// the __syncthreads between load and store phases. With j = t + k*256 the
// rolled neighbor phi[j+1] is in lane+1 of the same wave -> __shfl_down(1).
// Only lane 63 (exec-masked, 1/64 lanes) recomputes its neighbor directly.

#define NVERT 1024
#define ROWSTRIDE (2 + 2 * NVERT)
#define BLK 256

__device__ __forceinline__ float fast_atan2f(float y, float x) {
    const float a = __builtin_fabsf(y);
    const float b = __builtin_fabsf(x);
    const float mn = fminf(a, b);
    const float mx = fmaxf(a, b);
    // t = mn/mx via hardware v_rcp_f32 (~1 ulp). Guard mx==0/denormal -> t=0.
    float t = (mx > 1.17549435e-38f) ? mn * __builtin_amdgcn_rcpf(mx) : 0.0f;
    // minimax odd poly for atan on [0,1], max abs err ~2.4e-5 rad
    const float s = t * t;
    float p = -1.1721200e-02f;
    p = fmaf(p, s, 5.2653320e-02f);
    p = fmaf(p, s, -1.1643287e-01f);
    p = fmaf(p, s, 1.9354346e-01f);
    p = fmaf(p, s, -3.3262347e-01f);
    p = fmaf(p, s, 9.9997726e-01f);
    float r = t * p;
    // quadrant fixups (branchless -> v_cndmask)
    r = (a > b) ? (1.57079632679f - r) : r;   // |y| > |x|
    r = (x < 0.0f) ? (3.14159265359f - r) : r;
    return __builtin_copysignf(r, y);
}

__global__ __launch_bounds__(BLK) void calweight_kernel(const float* __restrict__ x,
                                                        float* __restrict__ out) {
    const int b = blockIdx.x;
    const int t = threadIdx.x;

    const float* __restrict__ xr = x + (size_t)b * ROWSTRIDE;
    const float colv = xr[0];
    const float rowv = xr[1];

    // (b*2050 + 2)*4 bytes is always 8B-aligned -> float2* cast is safe.
    const float2* __restrict__ verts = (const float2*)(xr + 2);
    float* __restrict__ orow = out + (size_t)b * NVERT;
    const int lane = t & 63;

#pragma unroll
    for (int k = 0; k < NVERT / BLK; ++k) {
        const int j = t + k * BLK;
        const float2 v = verts[j];               // dense dwordx2, coalesced
        const float phi = fast_atan2f(v.y - rowv, v.x - colv);
        float phin = __shfl_down(phi, 1, 64);    // lane l <- phi of j+1
        if (lane == 63) {                        // wave boundary: recompute
            const int jn = (j + 1) & (NVERT - 1);
            const float2 vn = verts[jn];
            phin = fast_atan2f(vn.y - rowv, vn.x - colv);
        }
        orow[j] = phi - phin;                    // dense dword, coalesced
    }
}

extern "C" void kernel_launch(void* const* d_in, const int* in_sizes, int n_in,
                              void* d_out, int out_size, void* d_ws, size_t ws_size,
                              hipStream_t stream) {
    const float* x = (const float*)d_in[0];
    float* out = (float*)d_out;
    const int B = in_sizes[0] / ROWSTRIDE;  // 16384
    calweight_kernel<<<B, BLK, 0, stream>>>(x, out);
}

// Round 6
// 204.738 us; speedup vs baseline: 1.0553x; 1.0553x over previous
//
#include <hip/hip_runtime.h>
#include <math.h>

// CalWeight: out[b,j] = phi[b,j] - phi[b,(j+1)%N]
//   phi[b,j] = atan2(verts_y[b,j] - row[b], verts_x[b,j] - col[b])
// x layout per row: [col, row, v0x, v0y, ..., v1023x, v1023y], stride 2050 f32.
//
// Evidence ledger (R1/R4/R5):
//  - R1 (OCML atan2) = 204.7 us, R4 (20-op poly atan2) = 205.3 us -> kernel
//    is memory-bound; VALU fully hidden. Kernel never appears in rocprof
//    top-5 (all slots are 79-80 us harness poison fills) -> kernel < 79 us.
//  - Composite accounting: harness restore (268 MB) + poisons (604 MB) at
//    ~6.4 TB/s ~= 137 us fixed + kernel floor (201.3 MB ~= 32 us) ~= 205 us
//    measured -> R4's kernel sits at its HBM floor.
//  - R5 (no-LDS shfl variant, dword stores, divergent wrap recompute)
//    REGRESSED to 216.1 -> this 2-phase LDS structure with float4 stores is
//    the best-known shape. Keep it.

#define NVERT 1024
#define ROWSTRIDE (2 + 2 * NVERT)
#define BLK 256

__device__ __forceinline__ float fast_atan2f(float y, float x) {
    const float a = __builtin_fabsf(y);
    const float b = __builtin_fabsf(x);
    const float mn = fminf(a, b);
    const float mx = fmaxf(a, b);
    // t = mn/mx via hardware v_rcp_f32 (~1 ulp). Guard mx==0/denormal -> t=0.
    float t = (mx > 1.17549435e-38f) ? mn * __builtin_amdgcn_rcpf(mx) : 0.0f;
    // minimax odd poly for atan on [0,1], max abs err ~2.4e-5 rad
    const float s = t * t;
    float p = -1.1721200e-02f;
    p = fmaf(p, s, 5.2653320e-02f);
    p = fmaf(p, s, -1.1643287e-01f);
    p = fmaf(p, s, 1.9354346e-01f);
    p = fmaf(p, s, -3.3262347e-01f);
    p = fmaf(p, s, 9.9997726e-01f);
    float r = t * p;
    // quadrant fixups (branchless -> v_cndmask)
    r = (a > b) ? (1.57079632679f - r) : r;   // |y| > |x|
    r = (x < 0.0f) ? (3.14159265359f - r) : r;
    return __builtin_copysignf(r, y);
}

__global__ __launch_bounds__(BLK) void calweight_kernel(const float* __restrict__ x,
                                                        float* __restrict__ out) {
    const int b = blockIdx.x;
    const int t = threadIdx.x;

    const float* __restrict__ xr = x + (size_t)b * ROWSTRIDE;
    const float colv = xr[0];
    const float rowv = xr[1];

    __shared__ float phi[NVERT];

    // Phase 1: coalesced float2 vertex loads (8B-aligned: (b*2050+2)*4 % 8 == 0).
    const float2* __restrict__ verts = (const float2*)(xr + 2);
#pragma unroll
    for (int k = 0; k < NVERT / BLK; ++k) {
        const int j = t + k * BLK;
        const float2 v = verts[j];
        phi[j] = fast_atan2f(v.y - rowv, v.x - colv);
    }
    __syncthreads();

    // Phase 2: 4 consecutive outputs per thread as one float4 store.
    float* __restrict__ orow = out + (size_t)b * NVERT;
    const int j0 = 4 * t;
    const float4 p = ((const float4*)phi)[t];
    const float pn = phi[(j0 + 4) & (NVERT - 1)];  // wrap: j=1023 -> phi[0]
    float4 r;
    r.x = p.x - p.y;
    r.y = p.y - p.z;
    r.z = p.z - p.w;
    r.w = p.w - pn;
    ((float4*)orow)[t] = r;
}

extern "C" void kernel_launch(void* const* d_in, const int* in_sizes, int n_in,
                              void* d_out, int out_size, void* d_ws, size_t ws_size,
                              hipStream_t stream) {
    const float* x = (const float*)d_in[0];
    float* out = (float*)d_out;
    const int B = in_sizes[0] / ROWSTRIDE;  // 16384
    calweight_kernel<<<B, BLK, 0, stream>>>(x, out);
}